// Round 1
// baseline (2730.468 us; speedup 1.0000x reference)
//
#include <hip/hip_runtime.h>
#include <cstdint>
#include <cstddef>

#define B_  32
#define L_  4096
#define FT_ 512
#define FS_ 512
#define H_  512
#define C_  1025   // FT + FS + 1

// ---------------------------------------------------------------------------
// Kernel 1: pack W1's text block into a contiguous, 16B-aligned [H][FT] array
// (W1 rows have stride 1025 floats = 4100 B, which breaks float4 alignment),
// and extract the coverage-channel weight w1c[h] = W1[h][1024].
// ---------------------------------------------------------------------------
__global__ void pack_w1_kernel(const float* __restrict__ W1,
                               float* __restrict__ Wt,
                               float* __restrict__ w1c) {
    int i = blockIdx.x * blockDim.x + threadIdx.x;
    const int n = H_ * FT_;
    for (int j = i; j < n; j += gridDim.x * blockDim.x) {
        int h = j >> 9;          // j / 512
        int f = j & 511;
        Wt[j] = W1[(size_t)h * C_ + f];
    }
    if (i < H_) w1c[i] = W1[(size_t)i * C_ + FT_ + FS_];
}

// ---------------------------------------------------------------------------
// Kernel 2: sconst[b][h] = b1[h] + sum_f W1[h][FT+f] * summary[b][f]
// One wave per (b,h); lanes stride over f (coalesced W1 row reads), then
// wave-reduce. 16384 waves total.
// ---------------------------------------------------------------------------
__global__ __launch_bounds__(256) void sconst_kernel(
        const float* __restrict__ W1, const float* __restrict__ summary,
        const float* __restrict__ b1, float* __restrict__ sconst) {
    int wid  = (blockIdx.x * 256 + threadIdx.x) >> 6;   // global wave id
    int lane = threadIdx.x & 63;
    int b = wid >> 9;        // wid / 512
    int h = wid & 511;
    const float* wrow = W1 + (size_t)h * C_ + FT_;
    const float* srow = summary + (size_t)b * FS_;
    float acc = 0.f;
    #pragma unroll
    for (int f = lane; f < FS_; f += 64) acc += wrow[f] * srow[f];
    #pragma unroll
    for (int off = 32; off > 0; off >>= 1) acc += __shfl_down(acc, off, 64);
    if (lane == 0) sconst[wid] = acc + b1[h];
}

// ---------------------------------------------------------------------------
// Kernel 3: logits[b][l] = b2 + sum_h W2[h]*tanh(Wt[h]·ts[b,l,:] +
//                                   sconst[b][h] + w1c[h]*cov[b][l])
// Block: 256 threads, 32 l-values (tile is 32*512 floats = 64 KB LDS).
// Thread (l = tid&31, hg = tid>>5) covers h in [hg*64, hg*64+64).
// ts tile stored as float4 with per-row XOR swizzle (k4 ^ (l&7)) so the
// 32 lanes of a half-wave (same k4, different l) spread across bank groups
// (4-way floor instead of 32-way at raw 2048 B stride).
// W1t row loads are uniform across each 32-lane group -> L1 broadcast.
// Blocks whose whole l-range is masked (l0 >= len) exit immediately.
// ---------------------------------------------------------------------------
#define TL 32
__global__ __launch_bounds__(256) void logits_kernel(
        const float* __restrict__ ts, const float* __restrict__ coverage,
        const int* __restrict__ text_length,
        const float* __restrict__ Wt, const float* __restrict__ w1c,
        const float* __restrict__ sconst, const float* __restrict__ W2,
        const float* __restrict__ b2, float* __restrict__ logits) {
    const int b  = blockIdx.y;
    const int l0 = blockIdx.x * TL;
    const int len = text_length[b];
    if (l0 >= len) return;   // uniform early-out before any barrier

    __shared__ float4 ts4[TL * 128];   // 64 KB

    // Stage tile (contiguous 64 KB region of ts) with XOR swizzle.
    const float4* src = (const float4*)(ts + ((size_t)b * L_ + l0) * FT_);
    for (int j = threadIdx.x; j < TL * 128; j += 256) {
        int l  = j >> 7;
        int k4 = j & 127;
        ts4[(l << 7) | (k4 ^ (l & 7))] = src[j];
    }
    __syncthreads();

    const int l  = threadIdx.x & 31;
    const int hg = threadIdx.x >> 5;      // 0..7
    const int lg = l0 + l;

    float partial = 0.f;
    if (lg < len) {
        const float cov = coverage[(size_t)b * L_ + lg];
        const float* sc = sconst + (size_t)b * H_;
        const int swz = l & 7;
        const float4* tbase = ts4 + (l << 7);
        const int h0 = hg * 64;
        for (int h = h0; h < h0 + 64; h += 2) {
            const float4* w0 = (const float4*)(Wt + (size_t)h * FT_);
            const float4* w1 = (const float4*)(Wt + (size_t)(h + 1) * FT_);
            float a0 = 0.f, a1 = 0.f;
            #pragma unroll 4
            for (int k4 = 0; k4 < 128; ++k4) {
                float4 t4 = tbase[k4 ^ swz];
                float4 wa = w0[k4];
                float4 wb = w1[k4];
                a0 += wa.x * t4.x + wa.y * t4.y + wa.z * t4.z + wa.w * t4.w;
                a1 += wb.x * t4.x + wb.y * t4.y + wb.z * t4.z + wb.w * t4.w;
            }
            float p0 = a0 + sc[h]     + w1c[h]     * cov;
            float p1 = a1 + sc[h + 1] + w1c[h + 1] * cov;
            partial += W2[h] * tanhf(p0) + W2[h + 1] * tanhf(p1);
        }
    }

    // Reuse tile LDS for the 8-way h-group reduction.
    __syncthreads();                       // everyone done reading ts4
    float* red = (float*)ts4;
    red[l * 8 + hg] = partial;
    __syncthreads();
    if (hg == 0 && lg < len) {
        float s = 0.f;
        #pragma unroll
        for (int g = 0; g < 8; ++g) s += red[l * 8 + g];
        logits[(size_t)b * L_ + lg] = s + b2[0];
    }
}

// ---------------------------------------------------------------------------
// Kernel 4: masked softmax over l per batch; writes attention to d_out and
// zero-inits the context region (consumed by kernel 5's atomics).
// ---------------------------------------------------------------------------
__global__ __launch_bounds__(256) void softmax_kernel(
        const float* __restrict__ logits, const int* __restrict__ text_length,
        float* __restrict__ attn_out, float* __restrict__ ctx_out) {
    const int b = blockIdx.x;
    const int len = text_length[b];
    const float* lg = logits + (size_t)b * L_;
    float* at = attn_out + (size_t)b * L_;
    __shared__ float sred[256];

    for (int f = threadIdx.x; f < FT_; f += 256) ctx_out[b * FT_ + f] = 0.f;

    float m = -INFINITY;
    for (int l = threadIdx.x; l < len; l += 256) m = fmaxf(m, lg[l]);
    sred[threadIdx.x] = m;
    __syncthreads();
    for (int s = 128; s > 0; s >>= 1) {
        if (threadIdx.x < s)
            sred[threadIdx.x] = fmaxf(sred[threadIdx.x], sred[threadIdx.x + s]);
        __syncthreads();
    }
    m = sred[0];
    __syncthreads();

    float sum = 0.f;
    for (int l = threadIdx.x; l < len; l += 256) sum += __expf(lg[l] - m);
    sred[threadIdx.x] = sum;
    __syncthreads();
    for (int s = 128; s > 0; s >>= 1) {
        if (threadIdx.x < s) sred[threadIdx.x] += sred[threadIdx.x + s];
        __syncthreads();
    }
    const float inv = 1.f / sred[0];

    for (int l = threadIdx.x; l < L_; l += 256)
        at[l] = (l < len) ? __expf(lg[l] - m) * inv : 0.f;
}

// ---------------------------------------------------------------------------
// Kernel 5: context[b][f] = sum_l attn[b][l] * ts[b][l][f]
// Block = (l-chunk of 512, b); lanes cover f via float2 (coalesced 2 KB rows);
// partials land in d_out via atomicAdd (16 adds per (b,f) worst case).
// Chunks fully beyond text_length are skipped (attn there is exactly 0).
// ---------------------------------------------------------------------------
#define LC 512
__global__ __launch_bounds__(256) void context_kernel(
        const float* __restrict__ ts, const float* __restrict__ attn,
        const int* __restrict__ text_length, float* __restrict__ ctx) {
    const int b  = blockIdx.y;
    const int l0 = blockIdx.x * LC;
    const int len = text_length[b];
    if (l0 >= len) return;
    const int lend = min(len, l0 + LC);
    const float* at = attn + (size_t)b * L_;
    float2 acc = {0.f, 0.f};
    for (int l = l0; l < lend; ++l) {
        const float a = at[l];
        const float2* row = (const float2*)(ts + ((size_t)b * L_ + l) * FT_);
        float2 v = row[threadIdx.x];
        acc.x += a * v.x;
        acc.y += a * v.y;
    }
    const int f = threadIdx.x * 2;
    atomicAdd(&ctx[b * FT_ + f],     acc.x);
    atomicAdd(&ctx[b * FT_ + f + 1], acc.y);
}

// ---------------------------------------------------------------------------
extern "C" void kernel_launch(void* const* d_in, const int* in_sizes, int n_in,
                              void* d_out, int out_size, void* d_ws, size_t ws_size,
                              hipStream_t stream) {
    const float* ts       = (const float*)d_in[0];  // [B,L,FT]
    const float* summary  = (const float*)d_in[1];  // [B,FS]
    const float* coverage = (const float*)d_in[2];  // [B,1,L]
    const float* W1       = (const float*)d_in[3];  // [H,C]
    const float* b1       = (const float*)d_in[4];  // [H]
    const float* W2       = (const float*)d_in[5];  // [1,H]
    const float* b2       = (const float*)d_in[6];  // [1]
    const int*   text_len = (const int*)d_in[7];    // [B]

    float* ctx_out  = (float*)d_out;                // [B,FT]
    float* attn_out = (float*)d_out + B_ * FT_;     // [B,1,L]

    // Workspace layout (bytes)
    char* ws = (char*)d_ws;
    float* Wt     = (float*)(ws);                               // H*FT   = 1 MB
    float* w1c    = (float*)(ws + (size_t)H_ * FT_ * 4);        // H      = 2 KB
    float* sconst = (float*)(ws + (size_t)H_ * FT_ * 4 + H_ * 4);           // B*H = 64 KB
    float* logits = (float*)(ws + (size_t)H_ * FT_ * 4 + H_ * 4 + B_ * H_ * 4); // B*L = 512 KB

    pack_w1_kernel<<<256, 256, 0, stream>>>(W1, Wt, w1c);
    sconst_kernel<<<(B_ * H_) / 4, 256, 0, stream>>>(W1, summary, b1, sconst);
    logits_kernel<<<dim3(L_ / TL, B_), 256, 0, stream>>>(
        ts, coverage, text_len, Wt, w1c, sconst, W2, b2, logits);
    softmax_kernel<<<B_, 256, 0, stream>>>(logits, text_len, attn_out, ctx_out);
    context_kernel<<<dim3(L_ / LC, B_), 256, 0, stream>>>(ts, attn_out, text_len, ctx_out);
}

// Round 2
// 842.655 us; speedup vs baseline: 3.2403x; 3.2403x over previous
//
#include <hip/hip_runtime.h>
#include <cstdint>
#include <cstddef>

#define B_  32
#define L_  4096
#define FT_ 512
#define FS_ 512
#define H_  512
#define C_  1025   // FT + FS + 1

typedef __attribute__((ext_vector_type(8))) short short8;   // 8 bf16 = 4 VGPRs
typedef __attribute__((ext_vector_type(4))) float float4v;  // MFMA C/D

// fp32 -> bf16 round-to-nearest-even
__device__ __forceinline__ short f2bf(float f) {
    union { float f; unsigned u; } v; v.f = f;
    unsigned r = v.u + 0x7FFF + ((v.u >> 16) & 1);
    return (short)(r >> 16);
}

__device__ __forceinline__ float fast_tanh(float x) {
    x = fminf(fmaxf(x, -15.f), 15.f);
    float e = __expf(2.f * x);
    return (e - 1.f) / (e + 1.f);
}

// ---------------------------------------------------------------------------
// Kernel 1: pack W1 text block -> bf16 Wtb[H][FT] (contiguous, 16B aligned),
// extract coverage weight w1c[h] = W1[h][1024] (fp32).
// ---------------------------------------------------------------------------
__global__ void pack_w1_kernel(const float* __restrict__ W1,
                               short* __restrict__ Wtb,
                               float* __restrict__ w1c) {
    int i = blockIdx.x * blockDim.x + threadIdx.x;
    const int n = H_ * FT_;
    for (int j = i; j < n; j += gridDim.x * blockDim.x) {
        int h = j >> 9;
        int f = j & 511;
        Wtb[j] = f2bf(W1[(size_t)h * C_ + f]);
    }
    if (i < H_) w1c[i] = W1[(size_t)i * C_ + FT_ + FS_];
}

// ---------------------------------------------------------------------------
// Kernel 2: sconst[b][h] = b1[h] + sum_f W1[h][FT+f] * summary[b][f]  (fp32)
// One wave per (b,h).
// ---------------------------------------------------------------------------
__global__ __launch_bounds__(256) void sconst_kernel(
        const float* __restrict__ W1, const float* __restrict__ summary,
        const float* __restrict__ b1, float* __restrict__ sconst) {
    int wid  = (blockIdx.x * 256 + threadIdx.x) >> 6;
    int lane = threadIdx.x & 63;
    int b = wid >> 9;
    int h = wid & 511;
    const float* wrow = W1 + (size_t)h * C_ + FT_;
    const float* srow = summary + (size_t)b * FS_;
    float acc = 0.f;
    #pragma unroll
    for (int f = lane; f < FS_; f += 64) acc += wrow[f] * srow[f];
    #pragma unroll
    for (int off = 32; off > 0; off >>= 1) acc += __shfl_down(acc, off, 64);
    if (lane == 0) sconst[wid] = acc + b1[h];
}

// ---------------------------------------------------------------------------
// Kernel 3 (MFMA): logits[b][l] = b2 + sum_h W2[h]*tanh(Wtb[h]·ts_bf16[b,l,:]
//                                  + sconst[b][h] + w1c[h]*cov[b][l])
//
// Block = 256 threads (4 waves), tile = 64 l. ts tile staged fp32->bf16 into
// 64 KB LDS with 16B-granule XOR swizzle (g ^ (l&7)) -> A-frag ds_read_b128
// at the 8-cycle floor (conflict-free). Wave w covers l rows [16w,16w+16);
// h-chunks of 64 (4 MFMA n-tiles), K fully unrolled per chunk. B-frags are
// dwordx4 streamed from bf16 Wtb (512 KB, L2-resident). Epilogue fuses
// sconst/coverage/tanh/W2 and a 16-lane shfl_xor reduction per row.
// mfma_f32_16x16x32_bf16: A[m=lane&15][k=quad*8+j], B[n=lane&15][k=quad*8+j],
// D: col=lane&15, row=quad*4+reg.
// ---------------------------------------------------------------------------
#define TL 64
__global__ __launch_bounds__(256) void logits_kernel(
        const float* __restrict__ ts, const float* __restrict__ coverage,
        const int* __restrict__ text_length,
        const short* __restrict__ Wtb, const float* __restrict__ w1c,
        const float* __restrict__ sconst, const float* __restrict__ W2,
        const float* __restrict__ b2, float* __restrict__ logits) {
    const int b  = blockIdx.y;
    const int l0 = blockIdx.x * TL;
    const int len = text_length[b];
    if (l0 >= len) return;   // uniform early-out before any barrier

    __shared__ short ts_lds[TL * 512];   // exactly 64 KB, XOR-swizzled

    // ---- stage: fp32 float4 -> 4×bf16, granule-swizzled LDS write ----
    const float4* src = (const float4*)(ts + ((size_t)b * L_ + l0) * FT_);
    for (int j = threadIdx.x; j < TL * 128; j += 256) {
        int l  = j >> 7;
        int f4 = j & 127;
        float4 v = src[j];
        int g    = f4 >> 1;        // 16B granule index (8 bf16)
        int half = f4 & 1;
        short4 p;
        p.x = f2bf(v.x); p.y = f2bf(v.y); p.z = f2bf(v.z); p.w = f2bf(v.w);
        *(short4*)(ts_lds + l * 512 + ((g ^ (l & 7)) << 3) + (half << 2)) = p;
    }
    __syncthreads();

    const int lane = threadIdx.x & 63;
    const int wv   = threadIdx.x >> 6;    // wave 0..3
    const int wl0  = wv << 4;             // wave's l base within tile
    const int col  = lane & 15;
    const int quad = lane >> 4;           // 0..3

    if (l0 + wl0 >= len) return;          // whole wave masked; no barriers left

    const int m = wl0 + col;              // A row within tile
    const int s = m & 7;                  // row swizzle key
    const float* sc_b = sconst + (size_t)b * H_;
    const float4 cov4 = *(const float4*)(coverage + (size_t)b * L_ + l0 + wl0 + (quad << 2));

    float partial[4] = {0.f, 0.f, 0.f, 0.f};

    for (int c = 0; c < 8; ++c) {
        const int h0 = c * 64;
        float4v acc[4];
        #pragma unroll
        for (int nt = 0; nt < 4; ++nt) acc[nt] = (float4v){0.f, 0.f, 0.f, 0.f};

        const short* b_base = Wtb + (size_t)(h0 + col) * FT_ + quad * 8;
        const short* a_row  = ts_lds + m * 512;

        #pragma unroll 4
        for (int ks = 0; ks < 16; ++ks) {
            short8 af = *(const short8*)(a_row + ((((ks << 2) + quad) ^ s) << 3));
            #pragma unroll
            for (int nt = 0; nt < 4; ++nt) {
                short8 bf = *(const short8*)(b_base + nt * (16 * FT_) + ks * 32);
                acc[nt] = __builtin_amdgcn_mfma_f32_16x16x32_bf16(af, bf, acc[nt], 0, 0, 0);
            }
        }

        #pragma unroll
        for (int nt = 0; nt < 4; ++nt) {
            const int h = h0 + nt * 16 + col;
            const float sc = sc_b[h];
            const float wc = w1c[h];
            const float w2 = W2[h];
            #pragma unroll
            for (int r = 0; r < 4; ++r) {
                float pre = acc[nt][r] + sc + wc * ((const float*)&cov4)[r];
                partial[r] += w2 * fast_tanh(pre);
            }
        }
    }

    // reduce across the 16 lanes sharing a row-quad
    #pragma unroll
    for (int r = 0; r < 4; ++r) {
        float v = partial[r];
        v += __shfl_xor(v, 8, 64);
        v += __shfl_xor(v, 4, 64);
        v += __shfl_xor(v, 2, 64);
        v += __shfl_xor(v, 1, 64);
        partial[r] = v;
    }
    if (col == 0) {
        const float bias2 = b2[0];
        #pragma unroll
        for (int r = 0; r < 4; ++r) {
            int lg = l0 + wl0 + (quad << 2) + r;
            if (lg < len) logits[(size_t)b * L_ + lg] = partial[r] + bias2;
        }
    }
}

// ---------------------------------------------------------------------------
// Kernel 4: masked softmax per batch; writes attention and zeroes context.
// ---------------------------------------------------------------------------
__global__ __launch_bounds__(256) void softmax_kernel(
        const float* __restrict__ logits, const int* __restrict__ text_length,
        float* __restrict__ attn_out, float* __restrict__ ctx_out) {
    const int b = blockIdx.x;
    const int len = text_length[b];
    const float* lg = logits + (size_t)b * L_;
    float* at = attn_out + (size_t)b * L_;
    __shared__ float sred[256];

    for (int f = threadIdx.x; f < FT_; f += 256) ctx_out[b * FT_ + f] = 0.f;

    float m = -INFINITY;
    for (int l = threadIdx.x; l < len; l += 256) m = fmaxf(m, lg[l]);
    sred[threadIdx.x] = m;
    __syncthreads();
    for (int s = 128; s > 0; s >>= 1) {
        if (threadIdx.x < s)
            sred[threadIdx.x] = fmaxf(sred[threadIdx.x], sred[threadIdx.x + s]);
        __syncthreads();
    }
    m = sred[0];
    __syncthreads();

    float sum = 0.f;
    for (int l = threadIdx.x; l < len; l += 256) sum += __expf(lg[l] - m);
    sred[threadIdx.x] = sum;
    __syncthreads();
    for (int s = 128; s > 0; s >>= 1) {
        if (threadIdx.x < s) sred[threadIdx.x] += sred[threadIdx.x + s];
        __syncthreads();
    }
    const float inv = 1.f / sred[0];

    for (int l = threadIdx.x; l < L_; l += 256)
        at[l] = (l < len) ? __expf(lg[l] - m) * inv : 0.f;
}

// ---------------------------------------------------------------------------
// Kernel 5: context[b][f] = sum_l attn[b][l] * ts[b][l][f]  (fp32 ts)
// ---------------------------------------------------------------------------
#define LC 512
__global__ __launch_bounds__(256) void context_kernel(
        const float* __restrict__ ts, const float* __restrict__ attn,
        const int* __restrict__ text_length, float* __restrict__ ctx) {
    const int b  = blockIdx.y;
    const int l0 = blockIdx.x * LC;
    const int len = text_length[b];
    if (l0 >= len) return;
    const int lend = min(len, l0 + LC);
    const float* at = attn + (size_t)b * L_;
    float2 acc = {0.f, 0.f};
    for (int l = l0; l < lend; ++l) {
        const float a = at[l];
        const float2* row = (const float2*)(ts + ((size_t)b * L_ + l) * FT_);
        float2 v = row[threadIdx.x];
        acc.x += a * v.x;
        acc.y += a * v.y;
    }
    const int f = threadIdx.x * 2;
    atomicAdd(&ctx[b * FT_ + f],     acc.x);
    atomicAdd(&ctx[b * FT_ + f + 1], acc.y);
}

// ---------------------------------------------------------------------------
extern "C" void kernel_launch(void* const* d_in, const int* in_sizes, int n_in,
                              void* d_out, int out_size, void* d_ws, size_t ws_size,
                              hipStream_t stream) {
    const float* ts       = (const float*)d_in[0];  // [B,L,FT]
    const float* summary  = (const float*)d_in[1];  // [B,FS]
    const float* coverage = (const float*)d_in[2];  // [B,1,L]
    const float* W1       = (const float*)d_in[3];  // [H,C]
    const float* b1       = (const float*)d_in[4];  // [H]
    const float* W2       = (const float*)d_in[5];  // [1,H]
    const float* b2       = (const float*)d_in[6];  // [1]
    const int*   text_len = (const int*)d_in[7];    // [B]

    float* ctx_out  = (float*)d_out;                // [B,FT]
    float* attn_out = (float*)d_out + B_ * FT_;     // [B,1,L]

    // Workspace layout (bytes, all 16B aligned)
    char* ws = (char*)d_ws;
    short* Wtb    = (short*)(ws);                        // H*FT bf16 = 512 KB
    float* w1c    = (float*)(ws + 524288);               // 2 KB
    float* sconst = (float*)(ws + 526336);               // B*H = 64 KB
    float* logits = (float*)(ws + 591872);               // B*L = 512 KB

    pack_w1_kernel<<<256, 256, 0, stream>>>(W1, Wtb, w1c);
    sconst_kernel<<<(B_ * H_) / 4, 256, 0, stream>>>(W1, summary, b1, sconst);
    logits_kernel<<<dim3(L_ / TL, B_), 256, 0, stream>>>(
        ts, coverage, text_len, Wtb, w1c, sconst, W2, b2, logits);
    softmax_kernel<<<B_, 256, 0, stream>>>(logits, text_len, attn_out, ctx_out);
    context_kernel<<<dim3(L_ / LC, B_), 256, 0, stream>>>(ts, attn_out, text_len, ctx_out);
}

// Round 3
// 542.462 us; speedup vs baseline: 5.0335x; 1.5534x over previous
//
#include <hip/hip_runtime.h>
#include <cstdint>
#include <cstddef>

#define B_  32
#define L_  4096
#define FT_ 512
#define FS_ 512
#define H_  512
#define C_  1025   // FT + FS + 1

typedef __attribute__((ext_vector_type(8))) short short8;   // 8 bf16 = 4 VGPRs
typedef __attribute__((ext_vector_type(4))) float float4v;  // MFMA C/D

// fp32 -> bf16 round-to-nearest-even
__device__ __forceinline__ short f2bf(float f) {
    union { float f; unsigned u; } v; v.f = f;
    unsigned r = v.u + 0x7FFF + ((v.u >> 16) & 1);
    return (short)(r >> 16);
}

// tanh(x) = 1 - 2/(e^2x + 1); graceful at +-inf (->+-1), cheap: exp + rcp.
__device__ __forceinline__ float fast_tanh(float x) {
    float e = __expf(2.f * x);
    return 1.f - 2.f * __builtin_amdgcn_rcpf(e + 1.f);
}

// ---------------------------------------------------------------------------
// Kernel 1: pack W1's text block into MFMA B-fragment order (bf16):
//   fragB[((t*16 + s)*64 + lane)*8 + j] = bf16(W1[t*16 + (lane&15)]
//                                              [s*32 + (lane>>4)*8 + j])
// so a wave's B-frag load for (n-tile t, k-step s) is one fully-coalesced
// 1 KB global_load_dwordx4 (lane-contiguous). Also extracts w1c[h]=W1[h][1024].
// ---------------------------------------------------------------------------
__global__ __launch_bounds__(256) void pack_w1_kernel(
        const float* __restrict__ W1, short* __restrict__ fragB,
        float* __restrict__ w1c) {
    int gid = blockIdx.x * 256 + threadIdx.x;   // granule id, 32*16*64 = 32768
    int lane = gid & 63;
    int ts_  = gid >> 6;        // t*16 + s
    int t = ts_ >> 4;
    int s = ts_ & 15;
    int h  = t * 16 + (lane & 15);
    int k0 = s * 32 + (lane >> 4) * 8;
    const float* src = W1 + (size_t)h * C_ + k0;
    short8 o;
    #pragma unroll
    for (int j = 0; j < 8; ++j) o[j] = f2bf(src[j]);
    *(short8*)(fragB + (size_t)gid * 8) = o;
    if (gid < H_) w1c[gid] = W1[(size_t)gid * C_ + FT_ + FS_];
}

// ---------------------------------------------------------------------------
// Kernel 2: sconst[b][h] = b1[h] + sum_f W1[h][FT+f] * summary[b][f]  (fp32)
// ---------------------------------------------------------------------------
__global__ __launch_bounds__(256) void sconst_kernel(
        const float* __restrict__ W1, const float* __restrict__ summary,
        const float* __restrict__ b1, float* __restrict__ sconst) {
    int wid  = (blockIdx.x * 256 + threadIdx.x) >> 6;
    int lane = threadIdx.x & 63;
    int b = wid >> 9;
    int h = wid & 511;
    const float* wrow = W1 + (size_t)h * C_ + FT_;
    const float* srow = summary + (size_t)b * FS_;
    float acc = 0.f;
    #pragma unroll
    for (int f = lane; f < FS_; f += 64) acc += wrow[f] * srow[f];
    #pragma unroll
    for (int off = 32; off > 0; off >>= 1) acc += __shfl_down(acc, off, 64);
    if (lane == 0) sconst[wid] = acc + b1[h];
}

// ---------------------------------------------------------------------------
// Kernel 3 (MFMA): per block: 64-l tile, ALL 512 h (4 waves x 128 h each).
// A (64l x 512k bf16) staged once in 64 KB XOR-swizzled LDS, shared by all
// waves. B-frags streamed from fragB (each element read ONCE per block,
// coalesced 1 KB loads). Wave tile 64l x 128h = 4 m-tiles x 8 n-tiles =
// 32 accumulators; per ks: 4 ds_read_b128 + 8 global loads + 32 MFMAs.
// Epilogue fuses sconst/coverage/tanh/W2, 16-lane shfl reduce, then a
// cross-wave LDS reduction (4 partials per l).
// mfma_f32_16x16x32_bf16: A[m=lane&15][k=quad*8+j], B[n=lane&15][k=quad*8+j],
// D: col(n)=lane&15, row(m)=quad*4+reg.
// ---------------------------------------------------------------------------
#define TL 64
__global__ __launch_bounds__(256, 2) void logits_kernel(
        const float* __restrict__ ts, const float* __restrict__ coverage,
        const int* __restrict__ text_length,
        const short* __restrict__ fragB, const float* __restrict__ w1c,
        const float* __restrict__ sconst, const float* __restrict__ W2,
        const float* __restrict__ b2, float* __restrict__ logits) {
    const int b  = blockIdx.y;
    const int l0 = blockIdx.x * TL;
    const int len = text_length[b];
    if (l0 >= len) return;   // uniform early-out before any barrier

    __shared__ short ts_lds[TL * 512];   // exactly 64 KB, XOR-swizzled

    // ---- stage: 2 float4 -> 1 short8 per iter, granule-swizzled ----
    const float4* src = (const float4*)(ts + ((size_t)b * L_ + l0) * FT_);
    for (int j = threadIdx.x; j < TL * 64; j += 256) {
        int l = j >> 6;
        int g = j & 63;                 // 16B granule within row
        float4 v0 = src[2 * j];
        float4 v1 = src[2 * j + 1];
        short8 p;
        p[0] = f2bf(v0.x); p[1] = f2bf(v0.y); p[2] = f2bf(v0.z); p[3] = f2bf(v0.w);
        p[4] = f2bf(v1.x); p[5] = f2bf(v1.y); p[6] = f2bf(v1.z); p[7] = f2bf(v1.w);
        *(short8*)(ts_lds + l * 512 + ((g ^ (l & 7)) << 3)) = p;
    }
    __syncthreads();

    const int lane = threadIdx.x & 63;
    const int wv   = threadIdx.x >> 6;    // wave 0..3 -> h-chunk [128wv,128wv+128)
    const int col  = lane & 15;
    const int quad = lane >> 4;
    const int swz  = col & 7;             // A-row swizzle key (row m = mt*16+col)

    const short* aBase = ts_lds + col * 512;                       // + mt*16*512
    const short* bBase = fragB + ((size_t)(wv * 8) * 16 + 0) * 512 + lane * 8;

    float4v acc[8][4];                    // [nt][mt]
    #pragma unroll
    for (int nt = 0; nt < 8; ++nt)
        #pragma unroll
        for (int mt = 0; mt < 4; ++mt)
            acc[nt][mt] = (float4v){0.f, 0.f, 0.f, 0.f};

    #pragma unroll 2
    for (int ks = 0; ks < 16; ++ks) {
        short8 af[4];
        const int ag = ((ks * 4 + quad) ^ swz) << 3;
        #pragma unroll
        for (int mt = 0; mt < 4; ++mt)
            af[mt] = *(const short8*)(aBase + mt * (16 * 512) + ag);
        short8 bf[8];
        #pragma unroll
        for (int nt = 0; nt < 8; ++nt)
            bf[nt] = *(const short8*)(bBase + (size_t)(nt * 16 + ks) * 512);
        #pragma unroll
        for (int nt = 0; nt < 8; ++nt)
            #pragma unroll
            for (int mt = 0; mt < 4; ++mt)
                acc[nt][mt] = __builtin_amdgcn_mfma_f32_16x16x32_bf16(
                    af[mt], bf[nt], acc[nt][mt], 0, 0, 0);
    }

    // ---- epilogue: tanh-weighted h-reduction ----
    const int h0 = wv * 128;
    const float* sc_b = sconst + (size_t)b * H_;
    float4 cov[4];
    #pragma unroll
    for (int mt = 0; mt < 4; ++mt)
        cov[mt] = *(const float4*)(coverage + (size_t)b * L_ + l0 + mt * 16 + quad * 4);

    float partial[4][4];                  // [mt][r], l = mt*16 + quad*4 + r
    #pragma unroll
    for (int mt = 0; mt < 4; ++mt)
        #pragma unroll
        for (int r = 0; r < 4; ++r) partial[mt][r] = 0.f;

    #pragma unroll
    for (int nt = 0; nt < 8; ++nt) {
        const int h = h0 + nt * 16 + col;
        const float sc = sc_b[h];
        const float wc = w1c[h];
        const float w2 = W2[h];
        #pragma unroll
        for (int mt = 0; mt < 4; ++mt)
            #pragma unroll
            for (int r = 0; r < 4; ++r) {
                float pre = acc[nt][mt][r] + sc + wc * ((const float*)&cov[mt])[r];
                partial[mt][r] += w2 * fast_tanh(pre);
            }
    }

    #pragma unroll
    for (int mt = 0; mt < 4; ++mt)
        #pragma unroll
        for (int r = 0; r < 4; ++r) {
            float v = partial[mt][r];
            v += __shfl_xor(v, 8, 64);
            v += __shfl_xor(v, 4, 64);
            v += __shfl_xor(v, 2, 64);
            v += __shfl_xor(v, 1, 64);
            partial[mt][r] = v;
        }

    __syncthreads();                      // done with ts_lds A-data
    float* red = (float*)ts_lds;          // 4 waves x 64 l partials
    if (col == 0) {
        #pragma unroll
        for (int mt = 0; mt < 4; ++mt)
            #pragma unroll
            for (int r = 0; r < 4; ++r)
                red[wv * 64 + mt * 16 + quad * 4 + r] = partial[mt][r];
    }
    __syncthreads();
    if (threadIdx.x < 64) {
        const int lg = l0 + threadIdx.x;
        if (lg < len) {
            float s = red[threadIdx.x] + red[64 + threadIdx.x] +
                      red[128 + threadIdx.x] + red[192 + threadIdx.x] + b2[0];
            logits[(size_t)b * L_ + lg] = s;
        }
    }
}

// ---------------------------------------------------------------------------
// Kernel 4: masked softmax per batch; writes attention to d_out.
// ---------------------------------------------------------------------------
__global__ __launch_bounds__(256) void softmax_kernel(
        const float* __restrict__ logits, const int* __restrict__ text_length,
        float* __restrict__ attn_out) {
    const int b = blockIdx.x;
    const int len = text_length[b];
    const float* lg = logits + (size_t)b * L_;
    float* at = attn_out + (size_t)b * L_;
    __shared__ float sred[256];

    float m = -INFINITY;
    for (int l = threadIdx.x; l < len; l += 256) m = fmaxf(m, lg[l]);
    sred[threadIdx.x] = m;
    __syncthreads();
    for (int s = 128; s > 0; s >>= 1) {
        if (threadIdx.x < s)
            sred[threadIdx.x] = fmaxf(sred[threadIdx.x], sred[threadIdx.x + s]);
        __syncthreads();
    }
    m = sred[0];
    __syncthreads();

    float sum = 0.f;
    for (int l = threadIdx.x; l < len; l += 256) sum += __expf(lg[l] - m);
    sred[threadIdx.x] = sum;
    __syncthreads();
    for (int s = 128; s > 0; s >>= 1) {
        if (threadIdx.x < s) sred[threadIdx.x] += sred[threadIdx.x + s];
        __syncthreads();
    }
    const float inv = 1.f / sred[0];

    for (int l = threadIdx.x; l < L_; l += 256)
        at[l] = (l < len) ? __expf(lg[l] - m) * inv : 0.f;
}

// ---------------------------------------------------------------------------
// Kernel 5a: per-(b, l-chunk) context partials -> workspace (NO atomics).
// Masked chunks write zeros (reduce sums all 8 unconditionally; ws is
// re-poisoned before every launch so we must write every slot).
// ---------------------------------------------------------------------------
#define LC 512
__global__ __launch_bounds__(256) void context_partial_kernel(
        const float* __restrict__ ts, const float* __restrict__ attn,
        const int* __restrict__ text_length, float* __restrict__ cpart) {
    const int b = blockIdx.y;
    const int c = blockIdx.x;
    const int l0 = c * LC;
    const int len = text_length[b];
    float2 acc = {0.f, 0.f};
    if (l0 < len) {
        const int lend = min(len, l0 + LC);
        const float* at = attn + (size_t)b * L_;
        const float2* row = (const float2*)(ts + ((size_t)b * L_ + l0) * FT_)
                            + threadIdx.x;
        for (int l = l0; l < lend; ++l, row += 256) {
            const float a = at[l];
            float2 v = *row;
            acc.x += a * v.x;
            acc.y += a * v.y;
        }
    }
    ((float2*)(cpart + (size_t)(b * 8 + c) * FT_))[threadIdx.x] = acc;
}

// ---------------------------------------------------------------------------
// Kernel 5b: reduce the 8 chunk-partials -> context output.
// ---------------------------------------------------------------------------
__global__ __launch_bounds__(256) void context_reduce_kernel(
        const float* __restrict__ cpart, float* __restrict__ ctx) {
    const int b = blockIdx.x;
    const float2* p = (const float2*)(cpart + (size_t)b * 8 * FT_);
    float2 s = {0.f, 0.f};
    #pragma unroll
    for (int c = 0; c < 8; ++c) {
        float2 v = p[c * 256 + threadIdx.x];
        s.x += v.x;
        s.y += v.y;
    }
    ((float2*)(ctx + (size_t)b * FT_))[threadIdx.x] = s;
}

// ---------------------------------------------------------------------------
extern "C" void kernel_launch(void* const* d_in, const int* in_sizes, int n_in,
                              void* d_out, int out_size, void* d_ws, size_t ws_size,
                              hipStream_t stream) {
    const float* ts       = (const float*)d_in[0];  // [B,L,FT]
    const float* summary  = (const float*)d_in[1];  // [B,FS]
    const float* coverage = (const float*)d_in[2];  // [B,1,L]
    const float* W1       = (const float*)d_in[3];  // [H,C]
    const float* b1       = (const float*)d_in[4];  // [H]
    const float* W2       = (const float*)d_in[5];  // [1,H]
    const float* b2       = (const float*)d_in[6];  // [1]
    const int*   text_len = (const int*)d_in[7];    // [B]

    float* ctx_out  = (float*)d_out;                // [B,FT]
    float* attn_out = (float*)d_out + B_ * FT_;     // [B,1,L]

    // Workspace layout (bytes, 16B aligned)
    char* ws = (char*)d_ws;
    short* fragB  = (short*)(ws);                   // 512 KB  @ 0
    float* w1c    = (float*)(ws + 524288);          // 2 KB
    float* sconst = (float*)(ws + 526336);          // 64 KB
    float* logits = (float*)(ws + 591872);          // 512 KB
    float* cpart  = (float*)(ws + 1116160);         // 512 KB  (ends 1640448)

    pack_w1_kernel<<<128, 256, 0, stream>>>(W1, fragB, w1c);
    sconst_kernel<<<(B_ * H_) / 4, 256, 0, stream>>>(W1, summary, b1, sconst);
    logits_kernel<<<dim3(L_ / TL, B_), 256, 0, stream>>>(
        ts, coverage, text_len, fragB, w1c, sconst, W2, b2, logits);
    softmax_kernel<<<B_, 256, 0, stream>>>(logits, text_len, attn_out);
    context_partial_kernel<<<dim3(L_ / LC, B_), 256, 0, stream>>>(
        ts, attn_out, text_len, cpart);
    context_reduce_kernel<<<B_, 256, 0, stream>>>(cpart, ctx_out);
}

// Round 4
// 425.159 us; speedup vs baseline: 6.4222x; 1.2759x over previous
//
#include <hip/hip_runtime.h>
#include <cstdint>
#include <cstddef>

#define B_  32
#define L_  4096
#define FT_ 512
#define FS_ 512
#define H_  512
#define C_  1025   // FT + FS + 1

typedef __attribute__((ext_vector_type(8))) short short8;   // 8 bf16 = 4 VGPRs
typedef __attribute__((ext_vector_type(4))) float float4v;  // MFMA C/D

// fp32 -> bf16 round-to-nearest-even
__device__ __forceinline__ short f2bf(float f) {
    union { float f; unsigned u; } v; v.f = f;
    unsigned r = v.u + 0x7FFF + ((v.u >> 16) & 1);
    return (short)(r >> 16);
}

// tanh(x) = 1 - 2/(e^2x + 1); graceful at +-inf (->+-1), cheap: exp + rcp.
__device__ __forceinline__ float fast_tanh(float x) {
    float e = __expf(2.f * x);
    return 1.f - 2.f * __builtin_amdgcn_rcpf(e + 1.f);
}

// ---------------------------------------------------------------------------
// Kernel 1 (fused prep): blocks [0,128) pack W1's text block into MFMA
// B-fragment order (bf16) + extract w1c; blocks [128, 128+4096) compute
// sconst[b][h] = b1[h] + W1[h, FT:FT+FS] . summary[b]  (one wave per (b,h)).
//   fragB[((t*16 + s)*64 + lane)*8 + j] = bf16(W1[t*16 + (lane&15)]
//                                              [s*32 + (lane>>4)*8 + j])
// ---------------------------------------------------------------------------
__global__ __launch_bounds__(256) void prep_kernel(
        const float* __restrict__ W1, const float* __restrict__ summary,
        const float* __restrict__ b1, short* __restrict__ fragB,
        float* __restrict__ w1c, float* __restrict__ sconst) {
    if (blockIdx.x < 128) {
        int gid = blockIdx.x * 256 + threadIdx.x;   // granule id, 32768 total
        int lane = gid & 63;
        int ts_  = gid >> 6;        // t*16 + s
        int t = ts_ >> 4;
        int s = ts_ & 15;
        int h  = t * 16 + (lane & 15);
        int k0 = s * 32 + (lane >> 4) * 8;
        const float* src = W1 + (size_t)h * C_ + k0;
        short8 o;
        #pragma unroll
        for (int j = 0; j < 8; ++j) o[j] = f2bf(src[j]);
        *(short8*)(fragB + (size_t)gid * 8) = o;
        if (gid < H_) w1c[gid] = W1[(size_t)gid * C_ + FT_ + FS_];
    } else {
        int wid  = ((blockIdx.x - 128) * 256 + threadIdx.x) >> 6;
        int lane = threadIdx.x & 63;
        int b = wid >> 9;
        int h = wid & 511;
        const float* wrow = W1 + (size_t)h * C_ + FT_;
        const float* srow = summary + (size_t)b * FS_;
        float acc = 0.f;
        #pragma unroll
        for (int f = lane; f < FS_; f += 64) acc += wrow[f] * srow[f];
        #pragma unroll
        for (int off = 32; off > 0; off >>= 1) acc += __shfl_down(acc, off, 64);
        if (lane == 0) sconst[wid] = acc + b1[h];
    }
}

// ---------------------------------------------------------------------------
// Kernel 2 (MFMA): per block: 64-l tile, ALL 512 h across 8 waves (64 h each).
// A (64l x 512k bf16) staged once in 64 KB XOR-swizzled LDS, shared by all
// waves. B-frags streamed from fragB (each element read ONCE per block,
// coalesced 1 KB wave-loads). Wave tile 64l x 64h = 4 m-tiles x 4 n-tiles =
// 16 accumulators (64 VGPR) -> __launch_bounds__(512,4) caps VGPR at 128 for
// 4 waves/SIMD (16 waves/CU, LDS allows exactly 2 blocks/CU).
// Epilogue fuses sconst/coverage/tanh/W2, 16-lane shfl reduce, then a
// cross-wave LDS reduction (8 partials per l).
// mfma_f32_16x16x32_bf16: A[m=lane&15][k=quad*8+j], B[n=lane&15][k=quad*8+j],
// D: col(n)=lane&15, row(m)=quad*4+reg.
// ---------------------------------------------------------------------------
#define TL 64
__global__ __launch_bounds__(512, 4) void logits_kernel(
        const float* __restrict__ ts, const float* __restrict__ coverage,
        const int* __restrict__ text_length,
        const short* __restrict__ fragB, const float* __restrict__ w1c,
        const float* __restrict__ sconst, const float* __restrict__ W2,
        const float* __restrict__ b2, float* __restrict__ logits) {
    const int b  = blockIdx.y;
    const int l0 = blockIdx.x * TL;
    const int len = text_length[b];
    if (l0 >= len) return;   // uniform early-out before any barrier

    __shared__ short ts_lds[TL * 512];   // exactly 64 KB, XOR-swizzled

    // ---- stage: 2 float4 -> 1 short8 per iter, granule-swizzled ----
    const float4* src = (const float4*)(ts + ((size_t)b * L_ + l0) * FT_);
    for (int j = threadIdx.x; j < TL * 64; j += 512) {
        int l = j >> 6;
        int g = j & 63;                 // 16B granule within row
        float4 v0 = src[2 * j];
        float4 v1 = src[2 * j + 1];
        short8 p;
        p[0] = f2bf(v0.x); p[1] = f2bf(v0.y); p[2] = f2bf(v0.z); p[3] = f2bf(v0.w);
        p[4] = f2bf(v1.x); p[5] = f2bf(v1.y); p[6] = f2bf(v1.z); p[7] = f2bf(v1.w);
        *(short8*)(ts_lds + l * 512 + ((g ^ (l & 7)) << 3)) = p;
    }
    __syncthreads();

    const int lane = threadIdx.x & 63;
    const int wv   = threadIdx.x >> 6;    // wave 0..7 -> h-chunk [64wv, 64wv+64)
    const int col  = lane & 15;
    const int quad = lane >> 4;
    const int swz  = col & 7;             // A-row swizzle key (row m = mt*16+col)

    const short* aBase = ts_lds + col * 512;                  // + mt*16*512
    const short* bBase = fragB + (size_t)(wv * 64) * 512 + lane * 8;

    float4v acc[4][4];                    // [nt][mt]
    #pragma unroll
    for (int nt = 0; nt < 4; ++nt)
        #pragma unroll
        for (int mt = 0; mt < 4; ++mt)
            acc[nt][mt] = (float4v){0.f, 0.f, 0.f, 0.f};

    #pragma unroll 2
    for (int ks = 0; ks < 16; ++ks) {
        short8 af[4];
        const int ag = ((ks * 4 + quad) ^ swz) << 3;
        #pragma unroll
        for (int mt = 0; mt < 4; ++mt)
            af[mt] = *(const short8*)(aBase + mt * (16 * 512) + ag);
        short8 bf[4];
        #pragma unroll
        for (int nt = 0; nt < 4; ++nt)
            bf[nt] = *(const short8*)(bBase + (size_t)(nt * 16 + ks) * 512);
        #pragma unroll
        for (int nt = 0; nt < 4; ++nt)
            #pragma unroll
            for (int mt = 0; mt < 4; ++mt)
                acc[nt][mt] = __builtin_amdgcn_mfma_f32_16x16x32_bf16(
                    af[mt], bf[nt], acc[nt][mt], 0, 0, 0);
    }

    // ---- epilogue: tanh-weighted h-reduction ----
    const int h0 = wv * 64;
    const float* sc_b = sconst + (size_t)b * H_;
    float4 cov[4];
    #pragma unroll
    for (int mt = 0; mt < 4; ++mt)
        cov[mt] = *(const float4*)(coverage + (size_t)b * L_ + l0 + mt * 16 + quad * 4);

    float partial[4][4];                  // [mt][r], l = mt*16 + quad*4 + r
    #pragma unroll
    for (int mt = 0; mt < 4; ++mt)
        #pragma unroll
        for (int r = 0; r < 4; ++r) partial[mt][r] = 0.f;

    #pragma unroll
    for (int nt = 0; nt < 4; ++nt) {
        const int h = h0 + nt * 16 + col;
        const float sc = sc_b[h];
        const float wc = w1c[h];
        const float w2 = W2[h];
        #pragma unroll
        for (int mt = 0; mt < 4; ++mt)
            #pragma unroll
            for (int r = 0; r < 4; ++r) {
                float pre = acc[nt][mt][r] + sc + wc * ((const float*)&cov[mt])[r];
                partial[mt][r] += w2 * fast_tanh(pre);
            }
    }

    #pragma unroll
    for (int mt = 0; mt < 4; ++mt)
        #pragma unroll
        for (int r = 0; r < 4; ++r) {
            float v = partial[mt][r];
            v += __shfl_xor(v, 8, 64);
            v += __shfl_xor(v, 4, 64);
            v += __shfl_xor(v, 2, 64);
            v += __shfl_xor(v, 1, 64);
            partial[mt][r] = v;
        }

    __syncthreads();                      // done with ts_lds A-data
    float* red = (float*)ts_lds;          // 8 waves x 64 l partials
    if (col == 0) {
        #pragma unroll
        for (int mt = 0; mt < 4; ++mt)
            #pragma unroll
            for (int r = 0; r < 4; ++r)
                red[wv * 64 + mt * 16 + quad * 4 + r] = partial[mt][r];
    }
    __syncthreads();
    if (threadIdx.x < 64) {
        const int lg = l0 + threadIdx.x;
        if (lg < len) {
            float s = b2[0];
            #pragma unroll
            for (int w = 0; w < 8; ++w) s += red[w * 64 + threadIdx.x];
            logits[(size_t)b * L_ + lg] = s;
        }
    }
}

// ---------------------------------------------------------------------------
// Kernel 3: masked softmax per batch; writes attention to d_out.
// ---------------------------------------------------------------------------
__global__ __launch_bounds__(1024) void softmax_kernel(
        const float* __restrict__ logits, const int* __restrict__ text_length,
        float* __restrict__ attn_out) {
    const int b = blockIdx.x;
    const int len = text_length[b];
    const float* lg = logits + (size_t)b * L_;
    float* at = attn_out + (size_t)b * L_;
    __shared__ float sred[1024];

    float m = -INFINITY;
    for (int l = threadIdx.x; l < len; l += 1024) m = fmaxf(m, lg[l]);
    sred[threadIdx.x] = m;
    __syncthreads();
    for (int s = 512; s > 0; s >>= 1) {
        if (threadIdx.x < s)
            sred[threadIdx.x] = fmaxf(sred[threadIdx.x], sred[threadIdx.x + s]);
        __syncthreads();
    }
    m = sred[0];
    __syncthreads();

    float sum = 0.f;
    for (int l = threadIdx.x; l < len; l += 1024) sum += __expf(lg[l] - m);
    sred[threadIdx.x] = sum;
    __syncthreads();
    for (int s = 512; s > 0; s >>= 1) {
        if (threadIdx.x < s) sred[threadIdx.x] += sred[threadIdx.x + s];
        __syncthreads();
    }
    const float inv = 1.f / sred[0];

    for (int l = threadIdx.x; l < L_; l += 1024)
        at[l] = (l < len) ? __expf(lg[l] - m) * inv : 0.f;
}

// ---------------------------------------------------------------------------
// Kernel 4a: per-(b, l-chunk) context partials -> workspace (NO atomics).
// 256 threads: lane group covers a full 512-float row as float4 (128 lanes),
// 2 l-rows in flight (lpar = tid>>7). Masked chunks write zeros (ws is
// re-poisoned before every launch, so every slot must be written).
// ---------------------------------------------------------------------------
#define LC 256
__global__ __launch_bounds__(256) void context_partial_kernel(
        const float* __restrict__ ts, const float* __restrict__ attn,
        const int* __restrict__ text_length, float* __restrict__ cpart) {
    const int b = blockIdx.y;
    const int c = blockIdx.x;
    const int l0 = c * LC;
    const int len = text_length[b];
    const int lpar = threadIdx.x >> 7;   // 0..1
    const int f4   = threadIdx.x & 127;
    float4 acc = {0.f, 0.f, 0.f, 0.f};
    if (l0 < len) {
        const int lend = min(len, l0 + LC);
        const float* at = attn + (size_t)b * L_;
        const float4* row = (const float4*)(ts + ((size_t)b * L_ + l0 + lpar) * FT_) + f4;
        for (int l = l0 + lpar; l < lend; l += 2, row += 256) {
            const float a = at[l];
            float4 v = *row;
            acc.x += a * v.x; acc.y += a * v.y;
            acc.z += a * v.z; acc.w += a * v.w;
        }
    }
    ((float4*)cpart)[(size_t)(((b * 16 + c) * 2 + lpar)) * 128 + f4] = acc;
}

// ---------------------------------------------------------------------------
// Kernel 4b: reduce the 32 chunk-partials per b -> context output.
// ---------------------------------------------------------------------------
__global__ __launch_bounds__(128) void context_reduce_kernel(
        const float* __restrict__ cpart, float* __restrict__ ctx) {
    const int b = blockIdx.x;
    const int t = threadIdx.x;           // 128 float4 lanes cover 512 floats
    float4 s = {0.f, 0.f, 0.f, 0.f};
    const float4* p = (const float4*)cpart + (size_t)b * 32 * 128 + t;
    #pragma unroll
    for (int c = 0; c < 32; ++c) {
        float4 v = p[c * 128];
        s.x += v.x; s.y += v.y; s.z += v.z; s.w += v.w;
    }
    ((float4*)ctx)[(size_t)b * 128 + t] = s;
}

// ---------------------------------------------------------------------------
extern "C" void kernel_launch(void* const* d_in, const int* in_sizes, int n_in,
                              void* d_out, int out_size, void* d_ws, size_t ws_size,
                              hipStream_t stream) {
    const float* ts       = (const float*)d_in[0];  // [B,L,FT]
    const float* summary  = (const float*)d_in[1];  // [B,FS]
    const float* coverage = (const float*)d_in[2];  // [B,1,L]
    const float* W1       = (const float*)d_in[3];  // [H,C]
    const float* b1       = (const float*)d_in[4];  // [H]
    const float* W2       = (const float*)d_in[5];  // [1,H]
    const float* b2       = (const float*)d_in[6];  // [1]
    const int*   text_len = (const int*)d_in[7];    // [B]

    float* ctx_out  = (float*)d_out;                // [B,FT]
    float* attn_out = (float*)d_out + B_ * FT_;     // [B,1,L]

    // Workspace layout (bytes, 16B aligned)
    char* ws = (char*)d_ws;
    short* fragB  = (short*)(ws);                   // 512 KB  @ 0
    float* w1c    = (float*)(ws + 524288);          // 2 KB
    float* sconst = (float*)(ws + 526336);          // 64 KB
    float* logits = (float*)(ws + 591872);          // 512 KB
    float* cpart  = (float*)(ws + 1116160);         // 2 MB   (ends 3213312)

    prep_kernel<<<128 + 4096, 256, 0, stream>>>(W1, summary, b1, fragB, w1c, sconst);
    logits_kernel<<<dim3(L_ / TL, B_), 512, 0, stream>>>(
        ts, coverage, text_len, fragB, w1c, sconst, W2, b2, logits);
    softmax_kernel<<<B_, 1024, 0, stream>>>(logits, text_len, attn_out);
    context_partial_kernel<<<dim3(L_ / LC, B_), 256, 0, stream>>>(
        ts, attn_out, text_len, cpart);
    context_reduce_kernel<<<B_, 128, 0, stream>>>(cpart, ctx_out);
}

// Round 5
// 420.188 us; speedup vs baseline: 6.4982x; 1.0118x over previous
//
#include <hip/hip_runtime.h>
#include <cstdint>
#include <cstddef>

#define B_  32
#define L_  4096
#define FT_ 512
#define FS_ 512
#define H_  512
#define C_  1025   // FT + FS + 1

typedef __attribute__((ext_vector_type(8))) short short8;   // 8 bf16 = 4 VGPRs
typedef __attribute__((ext_vector_type(4))) float float4v;  // MFMA C/D

// fp32 -> bf16 round-to-nearest-even
__device__ __forceinline__ short f2bf(float f) {
    union { float f; unsigned u; } v; v.f = f;
    unsigned r = v.u + 0x7FFF + ((v.u >> 16) & 1);
    return (short)(r >> 16);
}

// tanh(x) = 1 - 2/(e^2x + 1); graceful at +-inf (->+-1), cheap: exp + rcp.
__device__ __forceinline__ float fast_tanh(float x) {
    float e = __expf(2.f * x);
    return 1.f - 2.f * __builtin_amdgcn_rcpf(e + 1.f);
}

// ---------------------------------------------------------------------------
// Kernel 1 (fused prep): blocks [0,128) pack W1's text block into MFMA
// B-fragment order (bf16) + extract w1c; blocks [128, 128+4096) compute
// sconst[b][h] = b1[h] + W1[h, FT:FT+FS] . summary[b]  (one wave per (b,h)).
//   fragB[((t*16 + s)*64 + lane)*8 + j] = bf16(W1[t*16 + (lane&15)]
//                                              [s*32 + (lane>>4)*8 + j])
// ---------------------------------------------------------------------------
__global__ __launch_bounds__(256) void prep_kernel(
        const float* __restrict__ W1, const float* __restrict__ summary,
        const float* __restrict__ b1, short* __restrict__ fragB,
        float* __restrict__ w1c, float* __restrict__ sconst) {
    if (blockIdx.x < 128) {
        int gid = blockIdx.x * 256 + threadIdx.x;   // granule id, 32768 total
        int lane = gid & 63;
        int ts_  = gid >> 6;        // t*16 + s
        int t = ts_ >> 4;
        int s = ts_ & 15;
        int h  = t * 16 + (lane & 15);
        int k0 = s * 32 + (lane >> 4) * 8;
        const float* src = W1 + (size_t)h * C_ + k0;
        short8 o;
        #pragma unroll
        for (int j = 0; j < 8; ++j) o[j] = f2bf(src[j]);
        *(short8*)(fragB + (size_t)gid * 8) = o;
        if (gid < H_) w1c[gid] = W1[(size_t)gid * C_ + FT_ + FS_];
    } else {
        int wid  = ((blockIdx.x - 128) * 256 + threadIdx.x) >> 6;
        int lane = threadIdx.x & 63;
        int b = wid >> 9;
        int h = wid & 511;
        const float* wrow = W1 + (size_t)h * C_ + FT_;
        const float* srow = summary + (size_t)b * FS_;
        float acc = 0.f;
        #pragma unroll
        for (int f = lane; f < FS_; f += 64) acc += wrow[f] * srow[f];
        #pragma unroll
        for (int off = 32; off > 0; off >>= 1) acc += __shfl_down(acc, off, 64);
        if (lane == 0) sconst[wid] = acc + b1[h];
    }
}

// ---------------------------------------------------------------------------
// Kernel 2 (MFMA): per block: 32-l tile, ALL 512 h across 4 waves (128 h
// each). A (32l x 512k bf16) staged once in 32 KB XOR-swizzled LDS. B-frags
// streamed from fragB (each element read ONCE per block, coalesced 1 KB
// wave-loads). Wave tile 32l x 128h = 2 m-tiles x 8 n-tiles = 16 accumulators.
// __launch_bounds__(256,4): VGPR<=128, 4 blocks/CU (LDS 128KB of 160),
// finer text_length mask granularity + stage/compute overlap across blocks.
// Epilogue fuses sconst/coverage/tanh/W2, 16-lane shfl reduce, cross-wave
// LDS reduce. mfma_f32_16x16x32_bf16: A[m=lane&15][k=quad*8+j],
// B[n=lane&15][k=quad*8+j], D: col(n)=lane&15, row(m)=quad*4+reg.
// ---------------------------------------------------------------------------
#define TL 32
__global__ __launch_bounds__(256, 4) void logits_kernel(
        const float* __restrict__ ts, const float* __restrict__ coverage,
        const int* __restrict__ text_length,
        const short* __restrict__ fragB, const float* __restrict__ w1c,
        const float* __restrict__ sconst, const float* __restrict__ W2,
        const float* __restrict__ b2, float* __restrict__ logits) {
    const int b  = blockIdx.y;
    const int l0 = blockIdx.x * TL;
    const int len = text_length[b];
    if (l0 >= len) return;   // uniform early-out before any barrier

    __shared__ short ts_lds[TL * 512];   // 32 KB, XOR-swizzled

    // ---- stage: 2 float4 -> 1 short8 per iter, granule-swizzled ----
    const float4* src = (const float4*)(ts + ((size_t)b * L_ + l0) * FT_);
    for (int j = threadIdx.x; j < TL * 64; j += 256) {
        int l = j >> 6;
        int g = j & 63;                 // 16B granule within row
        float4 v0 = src[2 * j];
        float4 v1 = src[2 * j + 1];
        short8 p;
        p[0] = f2bf(v0.x); p[1] = f2bf(v0.y); p[2] = f2bf(v0.z); p[3] = f2bf(v0.w);
        p[4] = f2bf(v1.x); p[5] = f2bf(v1.y); p[6] = f2bf(v1.z); p[7] = f2bf(v1.w);
        *(short8*)(ts_lds + l * 512 + ((g ^ (l & 7)) << 3)) = p;
    }
    __syncthreads();

    const int lane = threadIdx.x & 63;
    const int wv   = threadIdx.x >> 6;    // wave 0..3 -> h-chunk [128wv,128wv+128)
    const int col  = lane & 15;
    const int quad = lane >> 4;
    const int swz  = col & 7;             // A-row swizzle key (row m = mt*16+col)

    const short* aBase = ts_lds + col * 512;                  // + mt*16*512
    const short* bBase = fragB + (size_t)(wv * 8) * 16 * 512 + lane * 8;

    float4v acc[8][2];                    // [nt][mt]
    #pragma unroll
    for (int nt = 0; nt < 8; ++nt)
        #pragma unroll
        for (int mt = 0; mt < 2; ++mt)
            acc[nt][mt] = (float4v){0.f, 0.f, 0.f, 0.f};

    #pragma unroll 2
    for (int ks = 0; ks < 16; ++ks) {
        short8 af[2];
        const int ag = ((ks * 4 + quad) ^ swz) << 3;
        #pragma unroll
        for (int mt = 0; mt < 2; ++mt)
            af[mt] = *(const short8*)(aBase + mt * (16 * 512) + ag);
        #pragma unroll
        for (int nt = 0; nt < 8; ++nt) {
            short8 bf = *(const short8*)(bBase + (size_t)(nt * 16 + ks) * 512);
            #pragma unroll
            for (int mt = 0; mt < 2; ++mt)
                acc[nt][mt] = __builtin_amdgcn_mfma_f32_16x16x32_bf16(
                    af[mt], bf, acc[nt][mt], 0, 0, 0);
        }
    }

    // ---- epilogue: tanh-weighted h-reduction ----
    const int h0 = wv * 128;
    const float* sc_b = sconst + (size_t)b * H_;
    float4 cov[2];
    #pragma unroll
    for (int mt = 0; mt < 2; ++mt)
        cov[mt] = *(const float4*)(coverage + (size_t)b * L_ + l0 + mt * 16 + quad * 4);

    float partial[2][4];                  // [mt][r], l = mt*16 + quad*4 + r
    #pragma unroll
    for (int mt = 0; mt < 2; ++mt)
        #pragma unroll
        for (int r = 0; r < 4; ++r) partial[mt][r] = 0.f;

    #pragma unroll
    for (int nt = 0; nt < 8; ++nt) {
        const int h = h0 + nt * 16 + col;
        const float sc = sc_b[h];
        const float wc = w1c[h];
        const float w2 = W2[h];
        #pragma unroll
        for (int mt = 0; mt < 2; ++mt)
            #pragma unroll
            for (int r = 0; r < 4; ++r) {
                float pre = acc[nt][mt][r] + sc + wc * ((const float*)&cov[mt])[r];
                partial[mt][r] += w2 * fast_tanh(pre);
            }
    }

    #pragma unroll
    for (int mt = 0; mt < 2; ++mt)
        #pragma unroll
        for (int r = 0; r < 4; ++r) {
            float v = partial[mt][r];
            v += __shfl_xor(v, 8, 64);
            v += __shfl_xor(v, 4, 64);
            v += __shfl_xor(v, 2, 64);
            v += __shfl_xor(v, 1, 64);
            partial[mt][r] = v;
        }

    __syncthreads();                      // done with ts_lds A-data
    float* red = (float*)ts_lds;          // 4 waves x 32 l partials
    if (col == 0) {
        #pragma unroll
        for (int mt = 0; mt < 2; ++mt)
            #pragma unroll
            for (int r = 0; r < 4; ++r)
                red[wv * 32 + mt * 16 + quad * 4 + r] = partial[mt][r];
    }
    __syncthreads();
    if (threadIdx.x < 32) {
        const int lg = l0 + threadIdx.x;
        if (lg < len) {
            float s = b2[0];
            #pragma unroll
            for (int w = 0; w < 4; ++w) s += red[w * 32 + threadIdx.x];
            logits[(size_t)b * L_ + lg] = s;
        }
    }
}

// ---------------------------------------------------------------------------
// Kernel 3: softmax STATS only (per-b max m and inv = 1/sum(exp)). 8 B out.
// ---------------------------------------------------------------------------
__global__ __launch_bounds__(1024) void softmax_stats_kernel(
        const float* __restrict__ logits, const int* __restrict__ text_length,
        float2* __restrict__ stats) {
    const int b = blockIdx.x;
    const int len = text_length[b];
    const float* lg = logits + (size_t)b * L_;
    __shared__ float sred[1024];

    float m = -INFINITY;
    for (int l = threadIdx.x; l < len; l += 1024) m = fmaxf(m, lg[l]);
    sred[threadIdx.x] = m;
    __syncthreads();
    for (int s = 512; s > 0; s >>= 1) {
        if (threadIdx.x < s)
            sred[threadIdx.x] = fmaxf(sred[threadIdx.x], sred[threadIdx.x + s]);
        __syncthreads();
    }
    m = sred[0];
    __syncthreads();

    float sum = 0.f;
    for (int l = threadIdx.x; l < len; l += 1024) sum += __expf(lg[l] - m);
    sred[threadIdx.x] = sum;
    __syncthreads();
    for (int s = 512; s > 0; s >>= 1) {
        if (threadIdx.x < s) sred[threadIdx.x] += sred[threadIdx.x + s];
        __syncthreads();
    }
    if (threadIdx.x == 0) {
        float2 st; st.x = m; st.y = 1.f / sred[0];
        stats[b] = st;
    }
}

// ---------------------------------------------------------------------------
// Kernel 4: fused attention + context partials. Per (b, 128-l chunk):
// threads<128 compute attn[l] = exp(logit-m)*inv (0 if masked), write it to
// d_out AND cache in LDS; then all 256 threads accumulate
// sum_l attn[l]*ts[b,l,:] (float4 rows, 2 l in flight) into cpart.
// Every cpart slot and every attn slot is written (ws/out re-poisoned).
// ---------------------------------------------------------------------------
#define LC 128
__global__ __launch_bounds__(256) void context_kernel(
        const float* __restrict__ ts, const float* __restrict__ logits,
        const float2* __restrict__ stats, const int* __restrict__ text_length,
        float* __restrict__ attn_out, float* __restrict__ cpart) {
    const int b = blockIdx.y;
    const int c = blockIdx.x;
    const int l0 = c * LC;
    const int len = text_length[b];
    const float2 st = stats[b];

    __shared__ float a_s[LC];
    if (threadIdx.x < LC) {
        const int l = l0 + threadIdx.x;
        float a = 0.f;
        if (l < len) a = __expf(logits[(size_t)b * L_ + l] - st.x) * st.y;
        a_s[threadIdx.x] = a;
        attn_out[(size_t)b * L_ + l] = a;
    }
    __syncthreads();

    const int lpar = threadIdx.x >> 7;   // 0..1
    const int f4   = threadIdx.x & 127;
    float4 acc = {0.f, 0.f, 0.f, 0.f};
    if (l0 < len) {
        const int lend = min(len - l0, LC);
        const float4* row = (const float4*)(ts + ((size_t)b * L_ + l0 + lpar) * FT_) + f4;
        for (int i = lpar; i < lend; i += 2, row += 256) {
            const float a = a_s[i];
            float4 v = *row;
            acc.x += a * v.x; acc.y += a * v.y;
            acc.z += a * v.z; acc.w += a * v.w;
        }
    }
    ((float4*)cpart)[(size_t)((b * 32 + c) * 2 + lpar) * 128 + f4] = acc;
}

// ---------------------------------------------------------------------------
// Kernel 5: reduce the 64 chunk-partials per b -> context output.
// ---------------------------------------------------------------------------
__global__ __launch_bounds__(128) void context_reduce_kernel(
        const float* __restrict__ cpart, float* __restrict__ ctx) {
    const int b = blockIdx.x;
    const int t = threadIdx.x;           // 128 float4 lanes cover 512 floats
    float4 s = {0.f, 0.f, 0.f, 0.f};
    const float4* p = (const float4*)cpart + (size_t)b * 64 * 128 + t;
    #pragma unroll
    for (int c = 0; c < 64; ++c) {
        float4 v = p[c * 128];
        s.x += v.x; s.y += v.y; s.z += v.z; s.w += v.w;
    }
    ((float4*)ctx)[(size_t)b * 128 + t] = s;
}

// ---------------------------------------------------------------------------
extern "C" void kernel_launch(void* const* d_in, const int* in_sizes, int n_in,
                              void* d_out, int out_size, void* d_ws, size_t ws_size,
                              hipStream_t stream) {
    const float* ts       = (const float*)d_in[0];  // [B,L,FT]
    const float* summary  = (const float*)d_in[1];  // [B,FS]
    const float* coverage = (const float*)d_in[2];  // [B,1,L]
    const float* W1       = (const float*)d_in[3];  // [H,C]
    const float* b1       = (const float*)d_in[4];  // [H]
    const float* W2       = (const float*)d_in[5];  // [1,H]
    const float* b2       = (const float*)d_in[6];  // [1]
    const int*   text_len = (const int*)d_in[7];    // [B]

    float* ctx_out  = (float*)d_out;                // [B,FT]
    float* attn_out = (float*)d_out + B_ * FT_;     // [B,1,L]

    // Workspace layout (bytes, 16B aligned)
    char* ws = (char*)d_ws;
    short*  fragB  = (short*)(ws);                  // 512 KB  @ 0
    float*  w1c    = (float*)(ws + 524288);         // 2 KB
    float*  sconst = (float*)(ws + 526336);         // 64 KB
    float*  logits = (float*)(ws + 591872);         // 512 KB
    float2* stats  = (float2*)(ws + 1116160);       // 256 B
    float*  cpart  = (float*)(ws + 1116672);        // 2 MB (ends ~3.2 MB)

    prep_kernel<<<128 + 4096, 256, 0, stream>>>(W1, summary, b1, fragB, w1c, sconst);
    logits_kernel<<<dim3(L_ / TL, B_), 256, 0, stream>>>(
        ts, coverage, text_len, fragB, w1c, sconst, W2, b2, logits);
    softmax_stats_kernel<<<B_, 1024, 0, stream>>>(logits, text_len, stats);
    context_kernel<<<dim3(L_ / LC, B_), 256, 0, stream>>>(
        ts, logits, stats, text_len, attn_out, cpart);
    context_reduce_kernel<<<B_, 128, 0, stream>>>(cpart, ctx_out);
}